// Round 7
// baseline (1705.599 us; speedup 1.0000x reference)
//
#include <hip/hip_runtime.h>

#define C_   256
#define HW_  1024
#define N_   16384
#define K_   8192
#define OUT_SZ   4194304
#define LOSS_OFF 4194304
#define IDX_OFF  4194305
#define GAP_T    0.01f   /* 3-product score error sigma ~3e-5 => 300-sigma margin (R5 telemetry: mmB=13 tiny-gap rows) */

typedef __attribute__((ext_vector_type(8)))  short short8;
typedef __attribute__((ext_vector_type(4)))  float f32x4;

// ---- ws layout (bytes), total 10,256,448 (R3/R5 proved ws_size >= this) ----
#define BH_OFF     0u          /* 4 MB: emb bf16 hi [8192][256] */
#define BL_OFF     4194304u    /* 4 MB: emb bf16 lo */
#define CNORM_OFF  8388608u    /* 32 KB */
#define S1_OFF     8421376u    /* 512 KB: bestS[row][8] */
#define S2_OFF     8945664u    /* 512 KB: secondS */
#define K1_OFF     9469952u    /* 512 KB: bestK */
#define LIST_OFF   9994240u    /* 64 KB (int) */
#define CNT_OFF    10059776u   /* 64 B */
#define FIDX_OFF   10059840u   /* 64 KB (int) */
#define WS_NEED    10256448u

// ---- fallback ws layout (round-1 proven) ----
#define FB_CNORM   0u
#define FB_BESTS   32768u
#define FB_BESTK   557056u
#define FB_FIDX    1081344u

__device__ __forceinline__ unsigned short f2bf_rne(float x) {
  unsigned u = __float_as_uint(x);
  unsigned r = (u + 0x7fffu + ((u >> 16) & 1u)) >> 16;
  return (unsigned short)r;
}
__device__ __forceinline__ float bf2f(unsigned short h) {
  return __uint_as_float(((unsigned)h) << 16);
}

__global__ __launch_bounds__(256) void k_norms(const float* __restrict__ emb,
                                               float* __restrict__ cnorm,
                                               float* __restrict__ loss_slot) {
  int tid = threadIdx.x, wave = tid >> 6, lane = tid & 63;
  int k = blockIdx.x * 4 + wave;
  float4 v = *(const float4*)(emb + k * C_ + lane * 4);
  float s = v.x*v.x + v.y*v.y + v.z*v.z + v.w*v.w;
  #pragma unroll
  for (int m = 32; m > 0; m >>= 1) s += __shfl_xor(s, m);
  if (lane == 0) cnorm[k] = 0.5f * s;
  if (blockIdx.x == 0 && tid == 0) *loss_slot = 0.0f;
}

// inputs [B,C,HW] fp32 -> row-major bf16 hi/lo A[n][c] (n=b*1024+hw), in d_out[0,16MB)
__global__ __launch_bounds__(256) void conv_inp2(const float* __restrict__ inp,
                                                 unsigned short* __restrict__ Ah,
                                                 unsigned short* __restrict__ Al) {
  __shared__ float T[64][65];
  int tid = threadIdx.x;
  int nt = blockIdx.x >> 2, ct = blockIdx.x & 3;
  int n0 = nt * 64, c0 = ct * 64;
  int b = n0 >> 10, hw0 = n0 & 1023;
  const float* base = inp + (size_t)b * (C_ * HW_) + hw0;
  #pragma unroll
  for (int i = 0; i < 16; ++i) {
    int cl = i * 4 + (tid >> 6), nl = tid & 63;
    T[nl][cl] = base[(size_t)(c0 + cl) * HW_ + nl];
  }
  __syncthreads();
  #pragma unroll
  for (int i = 0; i < 16; ++i) {
    int nl = i * 4 + (tid >> 6), cl = tid & 63;
    float x = T[nl][cl];
    unsigned short h = f2bf_rne(x);
    size_t o = (size_t)(n0 + nl) * C_ + c0 + cl;
    Ah[o] = h;
    Al[o] = f2bf_rne(x - bf2f(h));
  }
}

__global__ __launch_bounds__(256) void conv_emb2(const float* __restrict__ emb,
                                                 unsigned short* __restrict__ Bh,
                                                 unsigned short* __restrict__ Bl,
                                                 int* __restrict__ counter) {
  int e0 = (blockIdx.x * 256 + threadIdx.x) * 4;
  float4 v = *(const float4*)(emb + e0);
  float x[4] = {v.x, v.y, v.z, v.w};
  unsigned h[4], l[4];
  #pragma unroll
  for (int j = 0; j < 4; ++j) {
    unsigned short hh = f2bf_rne(x[j]);
    h[j] = hh;
    l[j] = f2bf_rne(x[j] - bf2f(hh));
  }
  uint2 ph, pl;
  ph.x = h[0] | (h[1] << 16); ph.y = h[2] | (h[3] << 16);
  pl.x = l[0] | (l[1] << 16); pl.y = l[2] | (l[3] << 16);
  *(uint2*)&Bh[e0] = ph;
  *(uint2*)&Bl[e0] = pl;
  if (blockIdx.x == 0 && threadIdx.x == 0) *counter = 0;
}

// bf16x2 3-product MFMA GEMM (R5-verified numerics; R6-verified end-to-end).
// R7: unpadded XOR-swizzled LDS (48 KB data vs 60 KB padded) -> 3 blocks/CU.
// chunk(row,ch) stored at row*32 + (ch^(row&3))*8 shorts; frag read uses quad^(qm&3).
// Bank math: word = 16*(qm&1) + 4*(quad^(qm&3)) -> every bank exactly 8 dword
// accesses per wave b128 (the 1KB floor), same as the padded layout.
__global__ __launch_bounds__(256, 3) void k_gemm3(const unsigned short* __restrict__ Ah,
                                                  const unsigned short* __restrict__ Al,
                                                  const unsigned short* __restrict__ Bh,
                                                  const unsigned short* __restrict__ Bl,
                                                  const float* __restrict__ cnorm,
                                                  float* __restrict__ bestS,
                                                  float* __restrict__ secondS,
                                                  int*   __restrict__ bestK) {
  // shorts: A hi [0,4096) | A lo [4096,8192) | B hi [8192,16384) | B lo [16384,24576)
  __shared__ __align__(16) unsigned short LDS[24576];
  __shared__ float mS1[2][128], mS2[2][128];          // wc-merge scratch
  __shared__ int   mK[2][128];

  const int tid = threadIdx.x, lane = tid & 63, wave = tid >> 6;
  const int wr = wave >> 1, wc = wave & 1;
  const int rb = blockIdx.x >> 3, kb = blockIdx.x & 7;
  const int row0 = rb * 128;
  const int qm = lane & 15, quad = lane >> 4;
  const int sw = (quad ^ (qm & 3)) * 8;               // swizzled k-chunk offset (shorts)

  float R1 = -3.4e38f, R2 = -3.4e38f; int RK = 0;     // thread tid<128 owns row row0+tid

  for (int sub = 0; sub < 4; ++sub) {
    const int nbe = kb * 4 + sub;
    f32x4 acc[4][8];
    #pragma unroll
    for (int r = 0; r < 4; ++r)
      #pragma unroll
      for (int c = 0; c < 8; ++c)
        #pragma unroll
        for (int e = 0; e < 4; ++e) acc[r][c][e] = 0.0f;

    for (int ci = 0; ci < 8; ++ci) {
      const int c0 = ci * 32;
      __syncthreads();
      #pragma unroll
      for (int j = 0; j < 4; ++j) {       // stage A hi+lo: 128 rows x 32 ch
        int half = j >> 1;
        int id2 = ((j & 1) << 8) + tid;
        int row = id2 >> 2, ch = id2 & 3;
        const unsigned short* src = (half ? Al : Ah) + (size_t)(row0 + row) * C_ + c0 + ch * 8;
        *(short8*)&LDS[half * 4096 + row * 32 + ((ch ^ (row & 3)) * 8)] = *(const short8*)src;
      }
      #pragma unroll
      for (int j = 0; j < 8; ++j) {       // stage B hi+lo: 256 codes x 32 ch
        int half = j >> 2;
        int id2 = ((j & 3) << 8) + tid;
        int r = id2 >> 2, ch = id2 & 3;
        const unsigned short* src = (half ? Bl : Bh) + (size_t)(nbe * 256 + r) * C_ + c0 + ch * 8;
        *(short8*)&LDS[8192 + half * 8192 + r * 32 + ((ch ^ (r & 3)) * 8)] = *(const short8*)src;
      }
      __syncthreads();

      short8 ah[4], al[4];
      #pragma unroll
      for (int rt = 0; rt < 4; ++rt) {
        int row = (wr * 4 + rt) * 16 + qm;             // A[m=lane&15][k=quad*8+j]; row&3 == qm&3
        ah[rt] = *(const short8*)&LDS[row * 32 + sw];
        al[rt] = *(const short8*)&LDS[4096 + row * 32 + sw];
      }
      #pragma unroll
      for (int ch2 = 0; ch2 < 2; ++ch2) {
        short8 bh[4], bl[4];
        #pragma unroll
        for (int q = 0; q < 4; ++q) {
          int ct = ch2 * 4 + q;
          int r = (wc * 8 + ct) * 16 + qm;             // B[n=lane&15][k=quad*8+j]; r&3 == qm&3
          bh[q] = *(const short8*)&LDS[8192 + r * 32 + sw];
          bl[q] = *(const short8*)&LDS[16384 + r * 32 + sw];
        }
        #pragma unroll
        for (int rt = 0; rt < 4; ++rt)
          #pragma unroll
          for (int q = 0; q < 4; ++q) {
            int ct = ch2 * 4 + q;
            acc[rt][ct] = __builtin_amdgcn_mfma_f32_16x16x32_bf16(ah[rt], bh[q], acc[rt][ct], 0, 0, 0);
            acc[rt][ct] = __builtin_amdgcn_mfma_f32_16x16x32_bf16(ah[rt], bl[q], acc[rt][ct], 0, 0, 0);
            acc[rt][ct] = __builtin_amdgcn_mfma_f32_16x16x32_bf16(al[rt], bh[q], acc[rt][ct], 0, 0, 0);
          }
      }
    }

    // per-sub epilogue: top-2 within this wave's 128-code half, then wc-merge via LDS
    const int colbase = nbe * 256 + wc * 128 + qm;     // C/D: col=lane&15, row=quad*4+reg
    float cn[8];
    #pragma unroll
    for (int ct = 0; ct < 8; ++ct) cn[ct] = cnorm[colbase + ct * 16];

    #pragma unroll
    for (int rt = 0; rt < 4; ++rt)
      #pragma unroll
      for (int rg = 0; rg < 4; ++rg) {
        float s1 = acc[rt][0][rg] - cn[0]; int k1 = colbase; float s2 = -3.4e38f;
        #pragma unroll
        for (int ct = 1; ct < 8; ++ct) {
          float s = acc[rt][ct][rg] - cn[ct];
          int  k  = colbase + ct * 16;
          if (s > s1) { s2 = s1; s1 = s; k1 = k; } else s2 = fmaxf(s2, s);
        }
        #pragma unroll
        for (int m = 1; m < 16; m <<= 1) {
          float o1 = __shfl_xor(s1, m); int ok = __shfl_xor(k1, m); float o2 = __shfl_xor(s2, m);
          if (o1 > s1 || (o1 == s1 && ok < k1)) { s2 = fmaxf(s1, o2); s1 = o1; k1 = ok; }
          else s2 = fmaxf(s2, o1);
        }
        if (qm == 0) {
          int rowl = wr * 64 + rt * 16 + quad * 4 + rg;
          mS1[wc][rowl] = s1; mS2[wc][rowl] = s2; mK[wc][rowl] = k1;
        }
      }
    __syncthreads();
    if (tid < 128) {                                    // merge wc halves (wc0 = lower k)
      float a1 = mS1[0][tid], a2 = mS2[0][tid]; int ak = mK[0][tid];
      float b1 = mS1[1][tid], b2 = mS2[1][tid]; int bk = mK[1][tid];
      float s1, s2; int k1;
      if (b1 > a1) { s1 = b1; k1 = bk; s2 = fmaxf(a1, b2); }
      else         { s1 = a1; k1 = ak; s2 = fmaxf(a2, b1); }
      if (s1 > R1) { R2 = fmaxf(R1, s2); R1 = s1; RK = k1; }   // subs ascend in k
      else R2 = fmaxf(R2, s1);
    }
    __syncthreads();
  }

  if (tid < 128) {
    int o = (row0 + tid) * 8 + kb;
    bestS[o] = R1; secondS[o] = R2; bestK[o] = RK;
  }
}

// merge 8 K-slices per row -> fidx + float idx output; flag small-gap rows into compact list
__global__ __launch_bounds__(256) void k_merge2(const float* __restrict__ bestS,
                                                const float* __restrict__ secondS,
                                                const int*   __restrict__ bestK,
                                                int* __restrict__ fidx,
                                                float* __restrict__ outIdx,
                                                int* __restrict__ list,
                                                int* __restrict__ counter) {
  int row = blockIdx.x * 256 + threadIdx.x;
  int base = row * 8;
  float g1 = -3.4e38f, g2 = -3.4e38f; int k1 = 0, wkb = 0;
  #pragma unroll
  for (int kb = 0; kb < 8; ++kb) {
    float s = bestS[base + kb];
    if (s > g1) { g2 = g1; g1 = s; k1 = bestK[base + kb]; wkb = kb; }
    else g2 = fmaxf(g2, s);
  }
  g2 = fmaxf(g2, secondS[base + wkb]);
  fidx[row] = k1;
  outIdx[row] = (float)k1;
  if (g1 - g2 < GAP_T) { int s = atomicAdd(counter, 1); list[s] = row; }
}

// exact fp32 rescue: one block per flagged row; f staged to LDS once; full 8192-code
// sweep with the round-1-proven ascending FMA chain (bit-identical scores); ties -> lowest k.
__global__ __launch_bounds__(256) void k_rescue2(const float* __restrict__ inp,
                                                 const float* __restrict__ emb,
                                                 const float* __restrict__ cnorm,
                                                 const int* __restrict__ list,
                                                 const int* __restrict__ counter,
                                                 int* __restrict__ fidx,
                                                 float* __restrict__ outIdx) {
  __shared__ float f[256];
  __shared__ float rs[4]; __shared__ int rk[4];
  int tid = threadIdx.x, lane = tid & 63, wv = tid >> 6;
  int count = *counter;
  for (int i = blockIdx.x; i < count; i += 512) {
    int row = list[i];
    __syncthreads();                                   // protect f across iterations
    f[tid] = inp[(size_t)(row >> 10) * (C_ * HW_) + (size_t)tid * HW_ + (row & 1023)];
    __syncthreads();
    float bs = -3.4e38f; int bk = 0;
    for (int kk = tid; kk < K_; kk += 256) {
      const float4* e4 = (const float4*)(emb + (size_t)kk * C_);
      float d = 0.0f;
      #pragma unroll
      for (int c4 = 0; c4 < 64; ++c4) {
        float4 e = e4[c4];
        d += f[c4*4]*e.x + f[c4*4+1]*e.y + f[c4*4+2]*e.z + f[c4*4+3]*e.w;
      }
      float s = d - cnorm[kk];
      if (s > bs) { bs = s; bk = kk; }                 // ascending kk: first-min ties
    }
    #pragma unroll
    for (int m = 1; m < 64; m <<= 1) {
      float so = __shfl_xor(bs, m); int ko = __shfl_xor(bk, m);
      if (so > bs || (so == bs && ko < bk)) { bs = so; bk = ko; }
    }
    if (lane == 0) { rs[wv] = bs; rk[wv] = bk; }
    __syncthreads();
    if (tid == 0) {
      #pragma unroll
      for (int w = 1; w < 4; ++w)
        if (rs[w] > bs || (rs[w] == bs && rk[w] < bk)) { bs = rs[w]; bk = rk[w]; }
      fidx[row] = bk; outIdx[row] = (float)bk;
    }
    __syncthreads();
  }
}

// gather emb[idx] -> NCHW output (overwrites the A-image scratch) + commitment loss
__global__ __launch_bounds__(256) void k_out(const float* __restrict__ inp,
                                             const float* __restrict__ emb,
                                             const int* __restrict__ fidx,
                                             float* __restrict__ out,
                                             float* __restrict__ loss) {
  __shared__ float Q[32][260];
  int tid = threadIdx.x;
  int n0 = blockIdx.x * 32, b = n0 >> 10, hw0 = n0 & 1023;
  #pragma unroll
  for (int p = 0; p < 8; ++p) {
    int r = p * 4 + (tid >> 6);
    int kq = fidx[n0 + r];
    float4 v = *(const float4*)(emb + (size_t)kq * C_ + (tid & 63) * 4);
    *(float4*)&Q[r][(tid & 63) * 4] = v;
  }
  __syncthreads();
  int hwl = tid & 31, cl = tid >> 5;
  float lsum = 0.0f;
  #pragma unroll
  for (int p = 0; p < 32; ++p) {
    int c = p * 8 + cl;
    size_t a = (size_t)b * (C_ * HW_) + (size_t)c * HW_ + hw0 + hwl;
    float q = Q[hwl][c];
    float x = inp[a];
    out[a] = q;
    float dd = q - x; lsum += dd * dd;
  }
  #pragma unroll
  for (int m = 32; m > 0; m >>= 1) lsum += __shfl_xor(lsum, m);
  __shared__ float red[4];
  if ((tid & 63) == 0) red[tid >> 6] = lsum;
  __syncthreads();
  if (tid == 0)
    atomicAdd(loss, (red[0] + red[1] + red[2] + red[3]) * (0.25f / (float)OUT_SZ));
}

// ---------------- fallback path (round-1 fp32, proven) ----------------
__global__ __launch_bounds__(256) void k_score_fb(const float* __restrict__ inp,
                                                  const float* __restrict__ emb,
                                                  const float* __restrict__ cnorm,
                                                  float* __restrict__ bestS,
                                                  int*   __restrict__ bestK) {
  __shared__ float As[16][132];
  __shared__ float Bs[16][132];
  const int tid = threadIdx.x;
  const int tx = tid & 15, ty = tid >> 4;
  const int rt = blockIdx.x >> 3, ks = blockIdx.x & 7;
  const int row0 = rt * 128;
  const float* Abase = inp + (row0 >> 10) * (C_ * HW_) + (row0 & 1023);
  const int kbase = ks * 1024;
  const int m4  = (tid & 31) << 2;
  const int ccA = tid >> 5;
  const int cc4 = (tid & 3) << 2;
  const int kkB = tid >> 2;

  float rS[8]; int rK[8];
  #pragma unroll
  for (int r = 0; r < 8; ++r) { rS[r] = -3.4e38f; rK[r] = 0; }

  for (int kt = 0; kt < 8; ++kt) {
    const int k0 = kbase + kt * 128;
    float acc[8][8];
    #pragma unroll
    for (int r = 0; r < 8; ++r)
      #pragma unroll
      for (int c = 0; c < 8; ++c) acc[r][c] = 0.f;

    for (int ci = 0; ci < 16; ++ci) {
      const int c0 = ci * 16;
      __syncthreads();
      #pragma unroll
      for (int p = 0; p < 2; ++p) {
        int cc = ccA + p * 8;
        float4 v = *(const float4*)(Abase + (c0 + cc) * HW_ + m4);
        *(float4*)(&As[cc][m4]) = v;
      }
      #pragma unroll
      for (int p = 0; p < 2; ++p) {
        int k = kkB + p * 64;
        float4 v = *(const float4*)(emb + (size_t)(k0 + k) * C_ + c0 + cc4);
        Bs[cc4 + 0][k] = v.x; Bs[cc4 + 1][k] = v.y;
        Bs[cc4 + 2][k] = v.z; Bs[cc4 + 3][k] = v.w;
      }
      __syncthreads();
      #pragma unroll
      for (int cc = 0; cc < 16; ++cc) {
        float4 a0 = *(const float4*)(&As[cc][ty * 8]);
        float4 a1 = *(const float4*)(&As[cc][ty * 8 + 4]);
        float4 b0 = *(const float4*)(&Bs[cc][tx * 8]);
        float4 b1 = *(const float4*)(&Bs[cc][tx * 8 + 4]);
        float a[8] = {a0.x, a0.y, a0.z, a0.w, a1.x, a1.y, a1.z, a1.w};
        float b[8] = {b0.x, b0.y, b0.z, b0.w, b1.x, b1.y, b1.z, b1.w};
        #pragma unroll
        for (int r = 0; r < 8; ++r)
          #pragma unroll
          for (int c = 0; c < 8; ++c) acc[r][c] += a[r] * b[c];
      }
    }
    float cn[8];
    {
      float4 c0v = *(const float4*)(cnorm + k0 + tx * 8);
      float4 c1v = *(const float4*)(cnorm + k0 + tx * 8 + 4);
      cn[0] = c0v.x; cn[1] = c0v.y; cn[2] = c0v.z; cn[3] = c0v.w;
      cn[4] = c1v.x; cn[5] = c1v.y; cn[6] = c1v.z; cn[7] = c1v.w;
    }
    #pragma unroll
    for (int r = 0; r < 8; ++r)
      #pragma unroll
      for (int c = 0; c < 8; ++c) {
        float s = acc[r][c] - cn[c];
        if (s > rS[r]) { rS[r] = s; rK[r] = k0 + tx * 8 + c; }
      }
  }
  #pragma unroll
  for (int r = 0; r < 8; ++r) {
    float s = rS[r]; int kk = rK[r];
    #pragma unroll
    for (int m = 1; m < 16; m <<= 1) {
      float so = __shfl_xor(s, m);
      int   ko = __shfl_xor(kk, m);
      if (so > s || (so == s && ko < kk)) { s = so; kk = ko; }
    }
    if (tx == 0) {
      int row = row0 + ty * 8 + r;
      bestS[ks * N_ + row] = s;
      bestK[ks * N_ + row] = kk;
    }
  }
}

__global__ __launch_bounds__(256) void k_merge_fb(const float* __restrict__ bestS,
                                                  const int*   __restrict__ bestK,
                                                  float* __restrict__ out_idx,
                                                  int*   __restrict__ fidx) {
  int n = blockIdx.x * 256 + threadIdx.x;
  float bs = -3.4e38f; int bk = 0x7fffffff;
  #pragma unroll
  for (int s = 0; s < 8; ++s) {
    float v = bestS[s * N_ + n];
    int  kk = bestK[s * N_ + n];
    if (v > bs || (v == bs && kk < bk)) { bs = v; bk = kk; }
  }
  out_idx[n] = (float)bk;
  fidx[n] = bk;
}

extern "C" void kernel_launch(void* const* d_in, const int* in_sizes, int n_in,
                              void* d_out, int out_size, void* d_ws, size_t ws_size,
                              hipStream_t stream) {
  const float* inp = (const float*)d_in[0];
  const float* emb = (const float*)d_in[1];
  float* out = (float*)d_out;
  char* ws = (char*)d_ws;

  if (ws_size >= (size_t)WS_NEED) {
    unsigned short* Ah = (unsigned short*)d_out;        // A image in d_out[0,16MB)
    unsigned short* Al = Ah + 4194304;                  // (k_out overwrites it last)
    unsigned short* Bh = (unsigned short*)(ws + BH_OFF);
    unsigned short* Bl = (unsigned short*)(ws + BL_OFF);
    float* cnorm = (float*)(ws + CNORM_OFF);
    float* S1    = (float*)(ws + S1_OFF);
    float* S2    = (float*)(ws + S2_OFF);
    int*   K1    = (int*)(ws + K1_OFF);
    int*   list    = (int*)(ws + LIST_OFF);
    int*   counter = (int*)(ws + CNT_OFF);
    int*   fidx    = (int*)(ws + FIDX_OFF);

    k_norms   <<<K_ / 4, 256, 0, stream>>>(emb, cnorm, out + LOSS_OFF);
    conv_inp2 <<<1024,   256, 0, stream>>>(inp, Ah, Al);
    conv_emb2 <<<2048,   256, 0, stream>>>(emb, Bh, Bl, counter);
    k_gemm3   <<<1024,   256, 0, stream>>>(Ah, Al, Bh, Bl, cnorm, S1, S2, K1);
    k_merge2  <<<N_/256, 256, 0, stream>>>(S1, S2, K1, fidx, out + IDX_OFF, list, counter);
    k_rescue2 <<<512,    256, 0, stream>>>(inp, emb, cnorm, list, counter, fidx, out + IDX_OFF);
    k_out     <<<N_/32,  256, 0, stream>>>(inp, emb, fidx, out, out + LOSS_OFF);
  } else {
    float* cnorm = (float*)(ws + FB_CNORM);
    float* bestS = (float*)(ws + FB_BESTS);
    int*   bestK = (int*)(ws + FB_BESTK);
    int*   fidx  = (int*)(ws + FB_FIDX);

    k_norms    <<<K_ / 4, 256, 0, stream>>>(emb, cnorm, out + LOSS_OFF);
    k_score_fb <<<1024,   256, 0, stream>>>(inp, emb, cnorm, bestS, bestK);
    k_merge_fb <<<N_/256, 256, 0, stream>>>(bestS, bestK, out + IDX_OFF, fidx);
    k_out      <<<N_/32,  256, 0, stream>>>(inp, emb, fidx, out, out + LOSS_OFF);
  }
}

// Round 8
// 643.023 us; speedup vs baseline: 2.6525x; 2.6525x over previous
//
#include <hip/hip_runtime.h>

#define C_   256
#define HW_  1024
#define N_   16384
#define K_   8192
#define OUT_SZ   4194304
#define LOSS_OFF 4194304
#define IDX_OFF  4194305
#define GAP_T    0.01f   /* validated R7: passes; ~300 sigma of 3-product error margin */

typedef __attribute__((ext_vector_type(8)))  short short8;
typedef __attribute__((ext_vector_type(4)))  float f32x4;

// ---- ws layout (bytes), total 10,256,448 (R3/R5 proved ws_size >= this) ----
#define BH_OFF     0u
#define BL_OFF     4194304u
#define CNORM_OFF  8388608u
#define S1_OFF     8421376u
#define S2_OFF     8945664u
#define K1_OFF     9469952u
#define LIST_OFF   9994240u
#define CNT_OFF    10059776u
#define FIDX_OFF   10059840u
#define WS_NEED    10256448u

// ---- fallback ws layout (round-1 proven) ----
#define FB_CNORM   0u
#define FB_BESTS   32768u
#define FB_BESTK   557056u
#define FB_FIDX    1081344u

__device__ __forceinline__ unsigned short f2bf_rne(float x) {
  unsigned u = __float_as_uint(x);
  unsigned r = (u + 0x7fffu + ((u >> 16) & 1u)) >> 16;
  return (unsigned short)r;
}
__device__ __forceinline__ float bf2f(unsigned short h) {
  return __uint_as_float(((unsigned)h) << 16);
}

__global__ __launch_bounds__(256) void k_norms(const float* __restrict__ emb,
                                               float* __restrict__ cnorm,
                                               float* __restrict__ loss_slot) {
  int tid = threadIdx.x, wave = tid >> 6, lane = tid & 63;
  int k = blockIdx.x * 4 + wave;
  float4 v = *(const float4*)(emb + k * C_ + lane * 4);
  float s = v.x*v.x + v.y*v.y + v.z*v.z + v.w*v.w;
  #pragma unroll
  for (int m = 32; m > 0; m >>= 1) s += __shfl_xor(s, m);
  if (lane == 0) cnorm[k] = 0.5f * s;
  if (blockIdx.x == 0 && tid == 0) *loss_slot = 0.0f;
}

// inputs [B,C,HW] fp32 -> row-major bf16 hi/lo A[n][c] (n=b*1024+hw), in d_out[0,16MB)
__global__ __launch_bounds__(256) void conv_inp2(const float* __restrict__ inp,
                                                 unsigned short* __restrict__ Ah,
                                                 unsigned short* __restrict__ Al) {
  __shared__ float T[64][65];
  int tid = threadIdx.x;
  int nt = blockIdx.x >> 2, ct = blockIdx.x & 3;
  int n0 = nt * 64, c0 = ct * 64;
  int b = n0 >> 10, hw0 = n0 & 1023;
  const float* base = inp + (size_t)b * (C_ * HW_) + hw0;
  #pragma unroll
  for (int i = 0; i < 16; ++i) {
    int cl = i * 4 + (tid >> 6), nl = tid & 63;
    T[nl][cl] = base[(size_t)(c0 + cl) * HW_ + nl];
  }
  __syncthreads();
  #pragma unroll
  for (int i = 0; i < 16; ++i) {
    int nl = i * 4 + (tid >> 6), cl = tid & 63;
    float x = T[nl][cl];
    unsigned short h = f2bf_rne(x);
    size_t o = (size_t)(n0 + nl) * C_ + c0 + cl;
    Ah[o] = h;
    Al[o] = f2bf_rne(x - bf2f(h));
  }
}

__global__ __launch_bounds__(256) void conv_emb2(const float* __restrict__ emb,
                                                 unsigned short* __restrict__ Bh,
                                                 unsigned short* __restrict__ Bl,
                                                 int* __restrict__ counter) {
  int e0 = (blockIdx.x * 256 + threadIdx.x) * 4;
  float4 v = *(const float4*)(emb + e0);
  float x[4] = {v.x, v.y, v.z, v.w};
  unsigned h[4], l[4];
  #pragma unroll
  for (int j = 0; j < 4; ++j) {
    unsigned short hh = f2bf_rne(x[j]);
    h[j] = hh;
    l[j] = f2bf_rne(x[j] - bf2f(hh));
  }
  uint2 ph, pl;
  ph.x = h[0] | (h[1] << 16); ph.y = h[2] | (h[3] << 16);
  pl.x = l[0] | (l[1] << 16); pl.y = l[2] | (l[3] << 16);
  *(uint2*)&Bh[e0] = ph;
  *(uint2*)&Bl[e0] = pl;
  if (blockIdx.x == 0 && threadIdx.x == 0) *counter = 0;
}

// bf16x2 3-product MFMA GEMM.
// R8: (256,2) restored (R7's (256,3) forced acc spill -> 5.9GB scratch traffic);
// XOR-swizzled LDS kept (R7: halved bank conflicts); staging software-pipelined:
// ci+1's global loads issue AFTER the compute barrier so load latency overlaps MFMA.
__global__ __launch_bounds__(256, 2) void k_gemm3(const unsigned short* __restrict__ Ah,
                                                  const unsigned short* __restrict__ Al,
                                                  const unsigned short* __restrict__ Bh,
                                                  const unsigned short* __restrict__ Bl,
                                                  const float* __restrict__ cnorm,
                                                  float* __restrict__ bestS,
                                                  float* __restrict__ secondS,
                                                  int*   __restrict__ bestK) {
  // shorts: A hi [0,4096) | A lo [4096,8192) | B hi [8192,16384) | B lo [16384,24576)
  __shared__ __align__(16) unsigned short LDS[24576];
  __shared__ float mS1[2][128], mS2[2][128];
  __shared__ int   mK[2][128];

  const int tid = threadIdx.x, lane = tid & 63, wave = tid >> 6;
  const int wr = wave >> 1, wc = wave & 1;
  const int rb = blockIdx.x >> 3, kb = blockIdx.x & 7;
  const int row0 = rb * 128;
  const int qm = lane & 15, quad = lane >> 4;
  const int sw = (quad ^ (qm & 3)) * 8;               // swizzled k-chunk offset (shorts)

  float R1 = -3.4e38f, R2 = -3.4e38f; int RK = 0;     // thread tid<128 owns row row0+tid

  short8 rA[4], rB[8];                                // staging registers (48 VGPRs)

  for (int sub = 0; sub < 4; ++sub) {
    const int nbe = kb * 4 + sub;

    auto load_stage = [&](int c0) {
      #pragma unroll
      for (int j = 0; j < 4; ++j) {
        int half = j >> 1;
        int id2 = ((j & 1) << 8) + tid;
        int row = id2 >> 2, ch = id2 & 3;
        rA[j] = *(const short8*)((half ? Al : Ah) + (size_t)(row0 + row) * C_ + c0 + ch * 8);
      }
      #pragma unroll
      for (int j = 0; j < 8; ++j) {
        int half = j >> 2;
        int id2 = ((j & 3) << 8) + tid;
        int r = id2 >> 2, ch = id2 & 3;
        rB[j] = *(const short8*)((half ? Bl : Bh) + (size_t)(nbe * 256 + r) * C_ + c0 + ch * 8);
      }
    };
    auto store_stage = [&]() {
      #pragma unroll
      for (int j = 0; j < 4; ++j) {
        int half = j >> 1;
        int id2 = ((j & 1) << 8) + tid;
        int row = id2 >> 2, ch = id2 & 3;
        *(short8*)&LDS[half * 4096 + row * 32 + ((ch ^ (row & 3)) * 8)] = rA[j];
      }
      #pragma unroll
      for (int j = 0; j < 8; ++j) {
        int half = j >> 2;
        int id2 = ((j & 3) << 8) + tid;
        int r = id2 >> 2, ch = id2 & 3;
        *(short8*)&LDS[8192 + half * 8192 + r * 32 + ((ch ^ (r & 3)) * 8)] = rB[j];
      }
    };

    f32x4 acc[4][8];
    #pragma unroll
    for (int r = 0; r < 4; ++r)
      #pragma unroll
      for (int c = 0; c < 8; ++c)
        #pragma unroll
        for (int e = 0; e < 4; ++e) acc[r][c][e] = 0.0f;

    load_stage(0);                                    // prologue (sub-boundary bubble accepted)

    #pragma unroll
    for (int ci = 0; ci < 8; ++ci) {
      __syncthreads();                                // prior iteration's LDS reads done
      store_stage();
      __syncthreads();
      if (ci < 7) load_stage((ci + 1) * 32);          // in flight during MFMA below

      short8 ah[4], al[4];
      #pragma unroll
      for (int rt = 0; rt < 4; ++rt) {
        int row = (wr * 4 + rt) * 16 + qm;            // A[m=lane&15][k=quad*8+j]; row&3 == qm&3
        ah[rt] = *(const short8*)&LDS[row * 32 + sw];
        al[rt] = *(const short8*)&LDS[4096 + row * 32 + sw];
      }
      #pragma unroll
      for (int ch2 = 0; ch2 < 2; ++ch2) {
        short8 bh[4], bl[4];
        #pragma unroll
        for (int q = 0; q < 4; ++q) {
          int ct = ch2 * 4 + q;
          int r = (wc * 8 + ct) * 16 + qm;            // B[n=lane&15][k=quad*8+j]; r&3 == qm&3
          bh[q] = *(const short8*)&LDS[8192 + r * 32 + sw];
          bl[q] = *(const short8*)&LDS[16384 + r * 32 + sw];
        }
        #pragma unroll
        for (int rt = 0; rt < 4; ++rt)
          #pragma unroll
          for (int q = 0; q < 4; ++q) {
            int ct = ch2 * 4 + q;
            acc[rt][ct] = __builtin_amdgcn_mfma_f32_16x16x32_bf16(ah[rt], bh[q], acc[rt][ct], 0, 0, 0);
            acc[rt][ct] = __builtin_amdgcn_mfma_f32_16x16x32_bf16(ah[rt], bl[q], acc[rt][ct], 0, 0, 0);
            acc[rt][ct] = __builtin_amdgcn_mfma_f32_16x16x32_bf16(al[rt], bh[q], acc[rt][ct], 0, 0, 0);
          }
      }
    }

    // per-sub epilogue: top-2 within this wave's 128-code half, then wc-merge via LDS
    const int colbase = nbe * 256 + wc * 128 + qm;    // C/D: col=lane&15, row=quad*4+reg
    float cn[8];
    #pragma unroll
    for (int ct = 0; ct < 8; ++ct) cn[ct] = cnorm[colbase + ct * 16];

    #pragma unroll
    for (int rt = 0; rt < 4; ++rt)
      #pragma unroll
      for (int rg = 0; rg < 4; ++rg) {
        float s1 = acc[rt][0][rg] - cn[0]; int k1 = colbase; float s2 = -3.4e38f;
        #pragma unroll
        for (int ct = 1; ct < 8; ++ct) {
          float s = acc[rt][ct][rg] - cn[ct];
          int  k  = colbase + ct * 16;
          if (s > s1) { s2 = s1; s1 = s; k1 = k; } else s2 = fmaxf(s2, s);
        }
        #pragma unroll
        for (int m = 1; m < 16; m <<= 1) {
          float o1 = __shfl_xor(s1, m); int ok = __shfl_xor(k1, m); float o2 = __shfl_xor(s2, m);
          if (o1 > s1 || (o1 == s1 && ok < k1)) { s2 = fmaxf(s1, o2); s1 = o1; k1 = ok; }
          else s2 = fmaxf(s2, o1);
        }
        if (qm == 0) {
          int rowl = wr * 64 + rt * 16 + quad * 4 + rg;
          mS1[wc][rowl] = s1; mS2[wc][rowl] = s2; mK[wc][rowl] = k1;
        }
      }
    __syncthreads();
    if (tid < 128) {                                   // merge wc halves (wc0 = lower k)
      float a1 = mS1[0][tid], a2 = mS2[0][tid]; int ak = mK[0][tid];
      float b1 = mS1[1][tid], b2 = mS2[1][tid]; int bk = mK[1][tid];
      float s1, s2; int k1;
      if (b1 > a1) { s1 = b1; k1 = bk; s2 = fmaxf(a1, b2); }
      else         { s1 = a1; k1 = ak; s2 = fmaxf(a2, b1); }
      if (s1 > R1) { R2 = fmaxf(R1, s2); R1 = s1; RK = k1; }   // subs ascend in k
      else R2 = fmaxf(R2, s1);
    }
    __syncthreads();
  }

  if (tid < 128) {
    int o = (row0 + tid) * 8 + kb;
    bestS[o] = R1; secondS[o] = R2; bestK[o] = RK;
  }
}

// merge 8 K-slices per row -> fidx + float idx output; flag small-gap rows into compact list
__global__ __launch_bounds__(256) void k_merge2(const float* __restrict__ bestS,
                                                const float* __restrict__ secondS,
                                                const int*   __restrict__ bestK,
                                                int* __restrict__ fidx,
                                                float* __restrict__ outIdx,
                                                int* __restrict__ list,
                                                int* __restrict__ counter) {
  int row = blockIdx.x * 256 + threadIdx.x;
  int base = row * 8;
  float g1 = -3.4e38f, g2 = -3.4e38f; int k1 = 0, wkb = 0;
  #pragma unroll
  for (int kb = 0; kb < 8; ++kb) {
    float s = bestS[base + kb];
    if (s > g1) { g2 = g1; g1 = s; k1 = bestK[base + kb]; wkb = kb; }
    else g2 = fmaxf(g2, s);
  }
  g2 = fmaxf(g2, secondS[base + wkb]);
  fidx[row] = k1;
  outIdx[row] = (float)k1;
  if (g1 - g2 < GAP_T) { int s = atomicAdd(counter, 1); list[s] = row; }
}

// exact fp32 rescue: one block per flagged row; full 8192-code sweep, proven FMA chain
__global__ __launch_bounds__(256) void k_rescue2(const float* __restrict__ inp,
                                                 const float* __restrict__ emb,
                                                 const float* __restrict__ cnorm,
                                                 const int* __restrict__ list,
                                                 const int* __restrict__ counter,
                                                 int* __restrict__ fidx,
                                                 float* __restrict__ outIdx) {
  __shared__ float f[256];
  __shared__ float rs[4]; __shared__ int rk[4];
  int tid = threadIdx.x, lane = tid & 63, wv = tid >> 6;
  int count = *counter;
  for (int i = blockIdx.x; i < count; i += 512) {
    int row = list[i];
    __syncthreads();
    f[tid] = inp[(size_t)(row >> 10) * (C_ * HW_) + (size_t)tid * HW_ + (row & 1023)];
    __syncthreads();
    float bs = -3.4e38f; int bk = 0;
    for (int kk = tid; kk < K_; kk += 256) {
      const float4* e4 = (const float4*)(emb + (size_t)kk * C_);
      float d = 0.0f;
      #pragma unroll
      for (int c4 = 0; c4 < 64; ++c4) {
        float4 e = e4[c4];
        d += f[c4*4]*e.x + f[c4*4+1]*e.y + f[c4*4+2]*e.z + f[c4*4+3]*e.w;
      }
      float s = d - cnorm[kk];
      if (s > bs) { bs = s; bk = kk; }
    }
    #pragma unroll
    for (int m = 1; m < 64; m <<= 1) {
      float so = __shfl_xor(bs, m); int ko = __shfl_xor(bk, m);
      if (so > bs || (so == bs && ko < bk)) { bs = so; bk = ko; }
    }
    if (lane == 0) { rs[wv] = bs; rk[wv] = bk; }
    __syncthreads();
    if (tid == 0) {
      #pragma unroll
      for (int w = 1; w < 4; ++w)
        if (rs[w] > bs || (rs[w] == bs && rk[w] < bk)) { bs = rs[w]; bk = rk[w]; }
      fidx[row] = bk; outIdx[row] = (float)bk;
    }
    __syncthreads();
  }
}

// gather emb[idx] -> NCHW output (overwrites the A-image scratch) + commitment loss
__global__ __launch_bounds__(256) void k_out(const float* __restrict__ inp,
                                             const float* __restrict__ emb,
                                             const int* __restrict__ fidx,
                                             float* __restrict__ out,
                                             float* __restrict__ loss) {
  __shared__ float Q[32][260];
  int tid = threadIdx.x;
  int n0 = blockIdx.x * 32, b = n0 >> 10, hw0 = n0 & 1023;
  #pragma unroll
  for (int p = 0; p < 8; ++p) {
    int r = p * 4 + (tid >> 6);
    int kq = fidx[n0 + r];
    float4 v = *(const float4*)(emb + (size_t)kq * C_ + (tid & 63) * 4);
    *(float4*)&Q[r][(tid & 63) * 4] = v;
  }
  __syncthreads();
  int hwl = tid & 31, cl = tid >> 5;
  float lsum = 0.0f;
  #pragma unroll
  for (int p = 0; p < 32; ++p) {
    int c = p * 8 + cl;
    size_t a = (size_t)b * (C_ * HW_) + (size_t)c * HW_ + hw0 + hwl;
    float q = Q[hwl][c];
    float x = inp[a];
    out[a] = q;
    float dd = q - x; lsum += dd * dd;
  }
  #pragma unroll
  for (int m = 32; m > 0; m >>= 1) lsum += __shfl_xor(lsum, m);
  __shared__ float red[4];
  if ((tid & 63) == 0) red[tid >> 6] = lsum;
  __syncthreads();
  if (tid == 0)
    atomicAdd(loss, (red[0] + red[1] + red[2] + red[3]) * (0.25f / (float)OUT_SZ));
}

// ---------------- fallback path (round-1 fp32, proven) ----------------
__global__ __launch_bounds__(256) void k_score_fb(const float* __restrict__ inp,
                                                  const float* __restrict__ emb,
                                                  const float* __restrict__ cnorm,
                                                  float* __restrict__ bestS,
                                                  int*   __restrict__ bestK) {
  __shared__ float As[16][132];
  __shared__ float Bs[16][132];
  const int tid = threadIdx.x;
  const int tx = tid & 15, ty = tid >> 4;
  const int rt = blockIdx.x >> 3, ks = blockIdx.x & 7;
  const int row0 = rt * 128;
  const float* Abase = inp + (row0 >> 10) * (C_ * HW_) + (row0 & 1023);
  const int kbase = ks * 1024;
  const int m4  = (tid & 31) << 2;
  const int ccA = tid >> 5;
  const int cc4 = (tid & 3) << 2;
  const int kkB = tid >> 2;

  float rS[8]; int rK[8];
  #pragma unroll
  for (int r = 0; r < 8; ++r) { rS[r] = -3.4e38f; rK[r] = 0; }

  for (int kt = 0; kt < 8; ++kt) {
    const int k0 = kbase + kt * 128;
    float acc[8][8];
    #pragma unroll
    for (int r = 0; r < 8; ++r)
      #pragma unroll
      for (int c = 0; c < 8; ++c) acc[r][c] = 0.f;

    for (int ci = 0; ci < 16; ++ci) {
      const int c0 = ci * 16;
      __syncthreads();
      #pragma unroll
      for (int p = 0; p < 2; ++p) {
        int cc = ccA + p * 8;
        float4 v = *(const float4*)(Abase + (c0 + cc) * HW_ + m4);
        *(float4*)(&As[cc][m4]) = v;
      }
      #pragma unroll
      for (int p = 0; p < 2; ++p) {
        int k = kkB + p * 64;
        float4 v = *(const float4*)(emb + (size_t)(k0 + k) * C_ + c0 + cc4);
        Bs[cc4 + 0][k] = v.x; Bs[cc4 + 1][k] = v.y;
        Bs[cc4 + 2][k] = v.z; Bs[cc4 + 3][k] = v.w;
      }
      __syncthreads();
      #pragma unroll
      for (int cc = 0; cc < 16; ++cc) {
        float4 a0 = *(const float4*)(&As[cc][ty * 8]);
        float4 a1 = *(const float4*)(&As[cc][ty * 8 + 4]);
        float4 b0 = *(const float4*)(&Bs[cc][tx * 8]);
        float4 b1 = *(const float4*)(&Bs[cc][tx * 8 + 4]);
        float a[8] = {a0.x, a0.y, a0.z, a0.w, a1.x, a1.y, a1.z, a1.w};
        float b[8] = {b0.x, b0.y, b0.z, b0.w, b1.x, b1.y, b1.z, b1.w};
        #pragma unroll
        for (int r = 0; r < 8; ++r)
          #pragma unroll
          for (int c = 0; c < 8; ++c) acc[r][c] += a[r] * b[c];
      }
    }
    float cn[8];
    {
      float4 c0v = *(const float4*)(cnorm + k0 + tx * 8);
      float4 c1v = *(const float4*)(cnorm + k0 + tx * 8 + 4);
      cn[0] = c0v.x; cn[1] = c0v.y; cn[2] = c0v.z; cn[3] = c0v.w;
      cn[4] = c1v.x; cn[5] = c1v.y; cn[6] = c1v.z; cn[7] = c1v.w;
    }
    #pragma unroll
    for (int r = 0; r < 8; ++r)
      #pragma unroll
      for (int c = 0; c < 8; ++c) {
        float s = acc[r][c] - cn[c];
        if (s > rS[r]) { rS[r] = s; rK[r] = k0 + tx * 8 + c; }
      }
  }
  #pragma unroll
  for (int r = 0; r < 8; ++r) {
    float s = rS[r]; int kk = rK[r];
    #pragma unroll
    for (int m = 1; m < 16; m <<= 1) {
      float so = __shfl_xor(s, m);
      int   ko = __shfl_xor(kk, m);
      if (so > s || (so == s && ko < kk)) { s = so; kk = ko; }
    }
    if (tx == 0) {
      int row = row0 + ty * 8 + r;
      bestS[ks * N_ + row] = s;
      bestK[ks * N_ + row] = kk;
    }
  }
}

__global__ __launch_bounds__(256) void k_merge_fb(const float* __restrict__ bestS,
                                                  const int*   __restrict__ bestK,
                                                  float* __restrict__ out_idx,
                                                  int*   __restrict__ fidx) {
  int n = blockIdx.x * 256 + threadIdx.x;
  float bs = -3.4e38f; int bk = 0x7fffffff;
  #pragma unroll
  for (int s = 0; s < 8; ++s) {
    float v = bestS[s * N_ + n];
    int  kk = bestK[s * N_ + n];
    if (v > bs || (v == bs && kk < bk)) { bs = v; bk = kk; }
  }
  out_idx[n] = (float)bk;
  fidx[n] = bk;
}

extern "C" void kernel_launch(void* const* d_in, const int* in_sizes, int n_in,
                              void* d_out, int out_size, void* d_ws, size_t ws_size,
                              hipStream_t stream) {
  const float* inp = (const float*)d_in[0];
  const float* emb = (const float*)d_in[1];
  float* out = (float*)d_out;
  char* ws = (char*)d_ws;

  if (ws_size >= (size_t)WS_NEED) {
    unsigned short* Ah = (unsigned short*)d_out;        // A image in d_out[0,16MB)
    unsigned short* Al = Ah + 4194304;                  // (k_out overwrites it last)
    unsigned short* Bh = (unsigned short*)(ws + BH_OFF);
    unsigned short* Bl = (unsigned short*)(ws + BL_OFF);
    float* cnorm = (float*)(ws + CNORM_OFF);
    float* S1    = (float*)(ws + S1_OFF);
    float* S2    = (float*)(ws + S2_OFF);
    int*   K1    = (int*)(ws + K1_OFF);
    int*   list    = (int*)(ws + LIST_OFF);
    int*   counter = (int*)(ws + CNT_OFF);
    int*   fidx    = (int*)(ws + FIDX_OFF);

    k_norms   <<<K_ / 4, 256, 0, stream>>>(emb, cnorm, out + LOSS_OFF);
    conv_inp2 <<<1024,   256, 0, stream>>>(inp, Ah, Al);
    conv_emb2 <<<2048,   256, 0, stream>>>(emb, Bh, Bl, counter);
    k_gemm3   <<<1024,   256, 0, stream>>>(Ah, Al, Bh, Bl, cnorm, S1, S2, K1);
    k_merge2  <<<N_/256, 256, 0, stream>>>(S1, S2, K1, fidx, out + IDX_OFF, list, counter);
    k_rescue2 <<<512,    256, 0, stream>>>(inp, emb, cnorm, list, counter, fidx, out + IDX_OFF);
    k_out     <<<N_/32,  256, 0, stream>>>(inp, emb, fidx, out, out + LOSS_OFF);
  } else {
    float* cnorm = (float*)(ws + FB_CNORM);
    float* bestS = (float*)(ws + FB_BESTS);
    int*   bestK = (int*)(ws + FB_BESTK);
    int*   fidx  = (int*)(ws + FB_FIDX);

    k_norms    <<<K_ / 4, 256, 0, stream>>>(emb, cnorm, out + LOSS_OFF);
    k_score_fb <<<1024,   256, 0, stream>>>(inp, emb, cnorm, bestS, bestK);
    k_merge_fb <<<N_/256, 256, 0, stream>>>(bestS, bestK, out + IDX_OFF, fidx);
    k_out      <<<N_/32,  256, 0, stream>>>(inp, emb, fidx, out, out + LOSS_OFF);
  }
}

// Round 9
// 562.412 us; speedup vs baseline: 3.0326x; 1.1433x over previous
//
#include <hip/hip_runtime.h>

#define C_   256
#define HW_  1024
#define N_   16384
#define K_   8192
#define OUT_SZ   4194304
#define LOSS_OFF 4194304
#define IDX_OFF  4194305
#define GAP_T    0.01f   /* validated R7/R8 */

typedef __attribute__((ext_vector_type(8)))  short short8;
typedef __attribute__((ext_vector_type(4)))  float f32x4;

// ---- ws layout (bytes), total 10,256,448 ----
#define BH_OFF     0u
#define BL_OFF     4194304u
#define CNORM_OFF  8388608u
#define S1_OFF     8421376u
#define S2_OFF     8945664u
#define K1_OFF     9469952u
#define LIST_OFF   9994240u
#define CNT_OFF    10059776u
#define FIDX_OFF   10059840u
#define WS_NEED    10256448u

// ---- fallback ws layout (round-1 proven) ----
#define FB_CNORM   0u
#define FB_BESTS   32768u
#define FB_BESTK   557056u
#define FB_FIDX    1081344u

__device__ __forceinline__ unsigned short f2bf_rne(float x) {
  unsigned u = __float_as_uint(x);
  unsigned r = (u + 0x7fffu + ((u >> 16) & 1u)) >> 16;
  return (unsigned short)r;
}
__device__ __forceinline__ float bf2f(unsigned short h) {
  return __uint_as_float(((unsigned)h) << 16);
}
__device__ __forceinline__ void gld16(const void* g, void* l) {
  __builtin_amdgcn_global_load_lds((const __attribute__((address_space(1))) unsigned*)g,
                                   (__attribute__((address_space(3))) unsigned*)l, 16, 0, 0);
}

__global__ __launch_bounds__(256) void k_norms(const float* __restrict__ emb,
                                               float* __restrict__ cnorm,
                                               float* __restrict__ loss_slot) {
  int tid = threadIdx.x, wave = tid >> 6, lane = tid & 63;
  int k = blockIdx.x * 4 + wave;
  float4 v = *(const float4*)(emb + k * C_ + lane * 4);
  float s = v.x*v.x + v.y*v.y + v.z*v.z + v.w*v.w;
  #pragma unroll
  for (int m = 32; m > 0; m >>= 1) s += __shfl_xor(s, m);
  if (lane == 0) cnorm[k] = 0.5f * s;
  if (blockIdx.x == 0 && tid == 0) *loss_slot = 0.0f;
}

// inputs [B,C,HW] fp32 -> row-major bf16 hi/lo A[n][c] (n=b*1024+hw), in d_out[0,16MB)
__global__ __launch_bounds__(256) void conv_inp2(const float* __restrict__ inp,
                                                 unsigned short* __restrict__ Ah,
                                                 unsigned short* __restrict__ Al) {
  __shared__ float T[64][65];
  int tid = threadIdx.x;
  int nt = blockIdx.x >> 2, ct = blockIdx.x & 3;
  int n0 = nt * 64, c0 = ct * 64;
  int b = n0 >> 10, hw0 = n0 & 1023;
  const float* base = inp + (size_t)b * (C_ * HW_) + hw0;
  #pragma unroll
  for (int i = 0; i < 16; ++i) {
    int cl = i * 4 + (tid >> 6), nl = tid & 63;
    T[nl][cl] = base[(size_t)(c0 + cl) * HW_ + nl];
  }
  __syncthreads();
  #pragma unroll
  for (int i = 0; i < 16; ++i) {
    int nl = i * 4 + (tid >> 6), cl = tid & 63;
    float x = T[nl][cl];
    unsigned short h = f2bf_rne(x);
    size_t o = (size_t)(n0 + nl) * C_ + c0 + cl;
    Ah[o] = h;
    Al[o] = f2bf_rne(x - bf2f(h));
  }
}

__global__ __launch_bounds__(256) void conv_emb2(const float* __restrict__ emb,
                                                 unsigned short* __restrict__ Bh,
                                                 unsigned short* __restrict__ Bl,
                                                 int* __restrict__ counter) {
  int e0 = (blockIdx.x * 256 + threadIdx.x) * 4;
  float4 v = *(const float4*)(emb + e0);
  float x[4] = {v.x, v.y, v.z, v.w};
  unsigned h[4], l[4];
  #pragma unroll
  for (int j = 0; j < 4; ++j) {
    unsigned short hh = f2bf_rne(x[j]);
    h[j] = hh;
    l[j] = f2bf_rne(x[j] - bf2f(hh));
  }
  uint2 ph, pl;
  ph.x = h[0] | (h[1] << 16); ph.y = h[2] | (h[3] << 16);
  pl.x = l[0] | (l[1] << 16); pl.y = l[2] | (l[3] << 16);
  *(uint2*)&Bh[e0] = ph;
  *(uint2*)&Bl[e0] = pl;
  if (blockIdx.x == 0 && threadIdx.x == 0) *counter = 0;
}

// bf16x2 3-product MFMA GEMM.
// R9: staging via global_load_lds (no VGPR round-trip -- R8's register staging spilled:
// WRITE 12->151MB). XOR-swizzled unpadded LDS is byte-contiguous in chunk order, so
// chunk g's LDS addr = g*16 = wave-uniform base + lane*16 -- exactly gld16's semantics.
// (256,2): 64x128 wave tile pins us at 2 blocks/CU (R7: (256,3) spills acc).
__global__ __launch_bounds__(256, 2) void k_gemm3(const unsigned short* __restrict__ Ah,
                                                  const unsigned short* __restrict__ Al,
                                                  const unsigned short* __restrict__ Bh,
                                                  const unsigned short* __restrict__ Bl,
                                                  const float* __restrict__ cnorm,
                                                  float* __restrict__ bestS,
                                                  float* __restrict__ secondS,
                                                  int*   __restrict__ bestK) {
  // shorts: A hi [0,4096) | A lo [4096,8192) | B hi [8192,16384) | B lo [16384,24576)
  // chunk layout: A chunk g at byte g*16 (g = half*512 + row*4 + (ch^(row&3)));
  //               B chunk g at byte 16384 + g*16 (g = half*1024 + r*4 + (ch^(r&3)))
  __shared__ __align__(16) unsigned short LDS[24576];
  __shared__ float mS1[2][128], mS2[2][128];
  __shared__ int   mK[2][128];

  const int tid = threadIdx.x, lane = tid & 63, wave = tid >> 6;
  const int wr = wave >> 1, wc = wave & 1;
  const int rb = blockIdx.x >> 3, kb = blockIdx.x & 7;
  const int row0 = rb * 128;
  const int qm = lane & 15, quad = lane >> 4;
  const int sw = (quad ^ (qm & 3)) * 8;               // swizzled k-chunk offset (shorts)

  float R1 = -3.4e38f, R2 = -3.4e38f; int RK = 0;     // thread tid<128 owns row row0+tid

  // per-thread staging descriptors (ci-invariant parts)
  const int gA   = tid;                                // A issues: g = t*256 + tid, t=0..3
  const int gB   = tid;                                // B issues: g = t*256 + tid, t=0..7

  for (int sub = 0; sub < 4; ++sub) {
    const int nbe = kb * 4 + sub;
    f32x4 acc[4][8];
    #pragma unroll
    for (int r = 0; r < 4; ++r)
      #pragma unroll
      for (int c = 0; c < 8; ++c)
        #pragma unroll
        for (int e = 0; e < 4; ++e) acc[r][c][e] = 0.0f;

    for (int ci = 0; ci < 8; ++ci) {
      const int c0 = ci * 32;
      __syncthreads();                                 // prior iteration's LDS reads done
      #pragma unroll
      for (int t = 0; t < 4; ++t) {                    // A hi+lo: 1024 chunks
        int g = t * 256 + gA;
        int half = g >> 9, c = g & 511;
        int row = c >> 2, chs = c & 3, ch = chs ^ (row & 3);
        const unsigned short* src = (half ? Al : Ah) + (size_t)(row0 + row) * C_ + c0 + ch * 8;
        gld16(src, (char*)LDS + g * 16);
      }
      #pragma unroll
      for (int t = 0; t < 8; ++t) {                    // B hi+lo: 2048 chunks
        int g = t * 256 + gB;
        int half = g >> 10, c = g & 1023;
        int r = c >> 2, chs = c & 3, ch = chs ^ (r & 3);
        const unsigned short* src = (half ? Bl : Bh) + (size_t)(nbe * 256 + r) * C_ + c0 + ch * 8;
        gld16(src, (char*)LDS + 16384 + g * 16);
      }
      __syncthreads();                                 // drains vmcnt before reads

      short8 ah[4], al[4];
      #pragma unroll
      for (int rt = 0; rt < 4; ++rt) {
        int row = (wr * 4 + rt) * 16 + qm;             // A[m=lane&15][k=quad*8+j]; row&3 == qm&3
        ah[rt] = *(const short8*)&LDS[row * 32 + sw];
        al[rt] = *(const short8*)&LDS[4096 + row * 32 + sw];
      }
      #pragma unroll
      for (int ch2 = 0; ch2 < 2; ++ch2) {
        short8 bh[4], bl[4];
        #pragma unroll
        for (int q = 0; q < 4; ++q) {
          int ct = ch2 * 4 + q;
          int r = (wc * 8 + ct) * 16 + qm;             // B[n=lane&15][k=quad*8+j]; r&3 == qm&3
          bh[q] = *(const short8*)&LDS[8192 + r * 32 + sw];
          bl[q] = *(const short8*)&LDS[16384 + r * 32 + sw];
        }
        #pragma unroll
        for (int rt = 0; rt < 4; ++rt)
          #pragma unroll
          for (int q = 0; q < 4; ++q) {
            int ct = ch2 * 4 + q;
            acc[rt][ct] = __builtin_amdgcn_mfma_f32_16x16x32_bf16(ah[rt], bh[q], acc[rt][ct], 0, 0, 0);
            acc[rt][ct] = __builtin_amdgcn_mfma_f32_16x16x32_bf16(ah[rt], bl[q], acc[rt][ct], 0, 0, 0);
            acc[rt][ct] = __builtin_amdgcn_mfma_f32_16x16x32_bf16(al[rt], bh[q], acc[rt][ct], 0, 0, 0);
          }
      }
    }

    // per-sub epilogue: top-2 within this wave's 128-code half, then wc-merge via LDS
    const int colbase = nbe * 256 + wc * 128 + qm;     // C/D: col=lane&15, row=quad*4+reg
    float cn[8];
    #pragma unroll
    for (int ct = 0; ct < 8; ++ct) cn[ct] = cnorm[colbase + ct * 16];

    #pragma unroll
    for (int rt = 0; rt < 4; ++rt)
      #pragma unroll
      for (int rg = 0; rg < 4; ++rg) {
        float s1 = acc[rt][0][rg] - cn[0]; int k1 = colbase; float s2 = -3.4e38f;
        #pragma unroll
        for (int ct = 1; ct < 8; ++ct) {
          float s = acc[rt][ct][rg] - cn[ct];
          int  k  = colbase + ct * 16;
          if (s > s1) { s2 = s1; s1 = s; k1 = k; } else s2 = fmaxf(s2, s);
        }
        #pragma unroll
        for (int m = 1; m < 16; m <<= 1) {
          float o1 = __shfl_xor(s1, m); int ok = __shfl_xor(k1, m); float o2 = __shfl_xor(s2, m);
          if (o1 > s1 || (o1 == s1 && ok < k1)) { s2 = fmaxf(s1, o2); s1 = o1; k1 = ok; }
          else s2 = fmaxf(s2, o1);
        }
        if (qm == 0) {
          int rowl = wr * 64 + rt * 16 + quad * 4 + rg;
          mS1[wc][rowl] = s1; mS2[wc][rowl] = s2; mK[wc][rowl] = k1;
        }
      }
    __syncthreads();
    if (tid < 128) {                                   // merge wc halves (wc0 = lower k)
      float a1 = mS1[0][tid], a2 = mS2[0][tid]; int ak = mK[0][tid];
      float b1 = mS1[1][tid], b2 = mS2[1][tid]; int bk = mK[1][tid];
      float s1, s2; int k1;
      if (b1 > a1) { s1 = b1; k1 = bk; s2 = fmaxf(a1, b2); }
      else         { s1 = a1; k1 = ak; s2 = fmaxf(a2, b1); }
      if (s1 > R1) { R2 = fmaxf(R1, s2); R1 = s1; RK = k1; }   // subs ascend in k
      else R2 = fmaxf(R2, s1);
    }
    __syncthreads();
  }

  if (tid < 128) {
    int o = (row0 + tid) * 8 + kb;
    bestS[o] = R1; secondS[o] = R2; bestK[o] = RK;
  }
}

// merge 8 K-slices per row -> fidx + float idx output; flag small-gap rows into compact list
__global__ __launch_bounds__(256) void k_merge2(const float* __restrict__ bestS,
                                                const float* __restrict__ secondS,
                                                const int*   __restrict__ bestK,
                                                int* __restrict__ fidx,
                                                float* __restrict__ outIdx,
                                                int* __restrict__ list,
                                                int* __restrict__ counter) {
  int row = blockIdx.x * 256 + threadIdx.x;
  int base = row * 8;
  float g1 = -3.4e38f, g2 = -3.4e38f; int k1 = 0, wkb = 0;
  #pragma unroll
  for (int kb = 0; kb < 8; ++kb) {
    float s = bestS[base + kb];
    if (s > g1) { g2 = g1; g1 = s; k1 = bestK[base + kb]; wkb = kb; }
    else g2 = fmaxf(g2, s);
  }
  g2 = fmaxf(g2, secondS[base + wkb]);
  fidx[row] = k1;
  outIdx[row] = (float)k1;
  if (g1 - g2 < GAP_T) { int s = atomicAdd(counter, 1); list[s] = row; }
}

// exact fp32 rescue: one block per flagged row; full 8192-code sweep, proven FMA chain
__global__ __launch_bounds__(256) void k_rescue2(const float* __restrict__ inp,
                                                 const float* __restrict__ emb,
                                                 const float* __restrict__ cnorm,
                                                 const int* __restrict__ list,
                                                 const int* __restrict__ counter,
                                                 int* __restrict__ fidx,
                                                 float* __restrict__ outIdx) {
  __shared__ float f[256];
  __shared__ float rs[4]; __shared__ int rk[4];
  int tid = threadIdx.x, lane = tid & 63, wv = tid >> 6;
  int count = *counter;
  for (int i = blockIdx.x; i < count; i += 512) {
    int row = list[i];
    __syncthreads();
    f[tid] = inp[(size_t)(row >> 10) * (C_ * HW_) + (size_t)tid * HW_ + (row & 1023)];
    __syncthreads();
    float bs = -3.4e38f; int bk = 0;
    for (int kk = tid; kk < K_; kk += 256) {
      const float4* e4 = (const float4*)(emb + (size_t)kk * C_);
      float d = 0.0f;
      #pragma unroll
      for (int c4 = 0; c4 < 64; ++c4) {
        float4 e = e4[c4];
        d += f[c4*4]*e.x + f[c4*4+1]*e.y + f[c4*4+2]*e.z + f[c4*4+3]*e.w;
      }
      float s = d - cnorm[kk];
      if (s > bs) { bs = s; bk = kk; }
    }
    #pragma unroll
    for (int m = 1; m < 64; m <<= 1) {
      float so = __shfl_xor(bs, m); int ko = __shfl_xor(bk, m);
      if (so > bs || (so == bs && ko < bk)) { bs = so; bk = ko; }
    }
    if (lane == 0) { rs[wv] = bs; rk[wv] = bk; }
    __syncthreads();
    if (tid == 0) {
      #pragma unroll
      for (int w = 1; w < 4; ++w)
        if (rs[w] > bs || (rs[w] == bs && rk[w] < bk)) { bs = rs[w]; bk = rk[w]; }
      fidx[row] = bk; outIdx[row] = (float)bk;
    }
    __syncthreads();
  }
}

// gather emb[idx] -> NCHW output (overwrites the A-image scratch) + commitment loss
__global__ __launch_bounds__(256) void k_out(const float* __restrict__ inp,
                                             const float* __restrict__ emb,
                                             const int* __restrict__ fidx,
                                             float* __restrict__ out,
                                             float* __restrict__ loss) {
  __shared__ float Q[32][260];
  int tid = threadIdx.x;
  int n0 = blockIdx.x * 32, b = n0 >> 10, hw0 = n0 & 1023;
  #pragma unroll
  for (int p = 0; p < 8; ++p) {
    int r = p * 4 + (tid >> 6);
    int kq = fidx[n0 + r];
    float4 v = *(const float4*)(emb + (size_t)kq * C_ + (tid & 63) * 4);
    *(float4*)&Q[r][(tid & 63) * 4] = v;
  }
  __syncthreads();
  int hwl = tid & 31, cl = tid >> 5;
  float lsum = 0.0f;
  #pragma unroll
  for (int p = 0; p < 32; ++p) {
    int c = p * 8 + cl;
    size_t a = (size_t)b * (C_ * HW_) + (size_t)c * HW_ + hw0 + hwl;
    float q = Q[hwl][c];
    float x = inp[a];
    out[a] = q;
    float dd = q - x; lsum += dd * dd;
  }
  #pragma unroll
  for (int m = 32; m > 0; m >>= 1) lsum += __shfl_xor(lsum, m);
  __shared__ float red[4];
  if ((tid & 63) == 0) red[tid >> 6] = lsum;
  __syncthreads();
  if (tid == 0)
    atomicAdd(loss, (red[0] + red[1] + red[2] + red[3]) * (0.25f / (float)OUT_SZ));
}

// ---------------- fallback path (round-1 fp32, proven) ----------------
__global__ __launch_bounds__(256) void k_score_fb(const float* __restrict__ inp,
                                                  const float* __restrict__ emb,
                                                  const float* __restrict__ cnorm,
                                                  float* __restrict__ bestS,
                                                  int*   __restrict__ bestK) {
  __shared__ float As[16][132];
  __shared__ float Bs[16][132];
  const int tid = threadIdx.x;
  const int tx = tid & 15, ty = tid >> 4;
  const int rt = blockIdx.x >> 3, ks = blockIdx.x & 7;
  const int row0 = rt * 128;
  const float* Abase = inp + (row0 >> 10) * (C_ * HW_) + (row0 & 1023);
  const int kbase = ks * 1024;
  const int m4  = (tid & 31) << 2;
  const int ccA = tid >> 5;
  const int cc4 = (tid & 3) << 2;
  const int kkB = tid >> 2;

  float rS[8]; int rK[8];
  #pragma unroll
  for (int r = 0; r < 8; ++r) { rS[r] = -3.4e38f; rK[r] = 0; }

  for (int kt = 0; kt < 8; ++kt) {
    const int k0 = kbase + kt * 128;
    float acc[8][8];
    #pragma unroll
    for (int r = 0; r < 8; ++r)
      #pragma unroll
      for (int c = 0; c < 8; ++c) acc[r][c] = 0.f;

    for (int ci = 0; ci < 16; ++ci) {
      const int c0 = ci * 16;
      __syncthreads();
      #pragma unroll
      for (int p = 0; p < 2; ++p) {
        int cc = ccA + p * 8;
        float4 v = *(const float4*)(Abase + (c0 + cc) * HW_ + m4);
        *(float4*)(&As[cc][m4]) = v;
      }
      #pragma unroll
      for (int p = 0; p < 2; ++p) {
        int k = kkB + p * 64;
        float4 v = *(const float4*)(emb + (size_t)(k0 + k) * C_ + c0 + cc4);
        Bs[cc4 + 0][k] = v.x; Bs[cc4 + 1][k] = v.y;
        Bs[cc4 + 2][k] = v.z; Bs[cc4 + 3][k] = v.w;
      }
      __syncthreads();
      #pragma unroll
      for (int cc = 0; cc < 16; ++cc) {
        float4 a0 = *(const float4*)(&As[cc][ty * 8]);
        float4 a1 = *(const float4*)(&As[cc][ty * 8 + 4]);
        float4 b0 = *(const float4*)(&Bs[cc][tx * 8]);
        float4 b1 = *(const float4*)(&Bs[cc][tx * 8 + 4]);
        float a[8] = {a0.x, a0.y, a0.z, a0.w, a1.x, a1.y, a1.z, a1.w};
        float b[8] = {b0.x, b0.y, b0.z, b0.w, b1.x, b1.y, b1.z, b1.w};
        #pragma unroll
        for (int r = 0; r < 8; ++r)
          #pragma unroll
          for (int c = 0; c < 8; ++c) acc[r][c] += a[r] * b[c];
      }
    }
    float cn[8];
    {
      float4 c0v = *(const float4*)(cnorm + k0 + tx * 8);
      float4 c1v = *(const float4*)(cnorm + k0 + tx * 8 + 4);
      cn[0] = c0v.x; cn[1] = c0v.y; cn[2] = c0v.z; cn[3] = c0v.w;
      cn[4] = c1v.x; cn[5] = c1v.y; cn[6] = c1v.z; cn[7] = c1v.w;
    }
    #pragma unroll
    for (int r = 0; r < 8; ++r)
      #pragma unroll
      for (int c = 0; c < 8; ++c) {
        float s = acc[r][c] - cn[c];
        if (s > rS[r]) { rS[r] = s; rK[r] = k0 + tx * 8 + c; }
      }
  }
  #pragma unroll
  for (int r = 0; r < 8; ++r) {
    float s = rS[r]; int kk = rK[r];
    #pragma unroll
    for (int m = 1; m < 16; m <<= 1) {
      float so = __shfl_xor(s, m);
      int   ko = __shfl_xor(kk, m);
      if (so > s || (so == s && ko < kk)) { s = so; kk = ko; }
    }
    if (tx == 0) {
      int row = row0 + ty * 8 + r;
      bestS[ks * N_ + row] = s;
      bestK[ks * N_ + row] = kk;
    }
  }
}

__global__ __launch_bounds__(256) void k_merge_fb(const float* __restrict__ bestS,
                                                  const int*   __restrict__ bestK,
                                                  float* __restrict__ out_idx,
                                                  int*   __restrict__ fidx) {
  int n = blockIdx.x * 256 + threadIdx.x;
  float bs = -3.4e38f; int bk = 0x7fffffff;
  #pragma unroll
  for (int s = 0; s < 8; ++s) {
    float v = bestS[s * N_ + n];
    int  kk = bestK[s * N_ + n];
    if (v > bs || (v == bs && kk < bk)) { bs = v; bk = kk; }
  }
  out_idx[n] = (float)bk;
  fidx[n] = bk;
}

extern "C" void kernel_launch(void* const* d_in, const int* in_sizes, int n_in,
                              void* d_out, int out_size, void* d_ws, size_t ws_size,
                              hipStream_t stream) {
  const float* inp = (const float*)d_in[0];
  const float* emb = (const float*)d_in[1];
  float* out = (float*)d_out;
  char* ws = (char*)d_ws;

  if (ws_size >= (size_t)WS_NEED) {
    unsigned short* Ah = (unsigned short*)d_out;        // A image in d_out[0,16MB)
    unsigned short* Al = Ah + 4194304;                  // (k_out overwrites it last)
    unsigned short* Bh = (unsigned short*)(ws + BH_OFF);
    unsigned short* Bl = (unsigned short*)(ws + BL_OFF);
    float* cnorm = (float*)(ws + CNORM_OFF);
    float* S1    = (float*)(ws + S1_OFF);
    float* S2    = (float*)(ws + S2_OFF);
    int*   K1    = (int*)(ws + K1_OFF);
    int*   list    = (int*)(ws + LIST_OFF);
    int*   counter = (int*)(ws + CNT_OFF);
    int*   fidx    = (int*)(ws + FIDX_OFF);

    k_norms   <<<K_ / 4, 256, 0, stream>>>(emb, cnorm, out + LOSS_OFF);
    conv_inp2 <<<1024,   256, 0, stream>>>(inp, Ah, Al);
    conv_emb2 <<<2048,   256, 0, stream>>>(emb, Bh, Bl, counter);
    k_gemm3   <<<1024,   256, 0, stream>>>(Ah, Al, Bh, Bl, cnorm, S1, S2, K1);
    k_merge2  <<<N_/256, 256, 0, stream>>>(S1, S2, K1, fidx, out + IDX_OFF, list, counter);
    k_rescue2 <<<512,    256, 0, stream>>>(inp, emb, cnorm, list, counter, fidx, out + IDX_OFF);
    k_out     <<<N_/32,  256, 0, stream>>>(inp, emb, fidx, out, out + LOSS_OFF);
  } else {
    float* cnorm = (float*)(ws + FB_CNORM);
    float* bestS = (float*)(ws + FB_BESTS);
    int*   bestK = (int*)(ws + FB_BESTK);
    int*   fidx  = (int*)(ws + FB_FIDX);

    k_norms    <<<K_ / 4, 256, 0, stream>>>(emb, cnorm, out + LOSS_OFF);
    k_score_fb <<<1024,   256, 0, stream>>>(inp, emb, cnorm, bestS, bestK);
    k_merge_fb <<<N_/256, 256, 0, stream>>>(bestS, bestK, out + IDX_OFF, fidx);
    k_out      <<<N_/32,  256, 0, stream>>>(inp, emb, fidx, out, out + LOSS_OFF);
  }
}

// Round 10
// 433.673 us; speedup vs baseline: 3.9329x; 1.2969x over previous
//
#include <hip/hip_runtime.h>

#define C_   256
#define HW_  1024
#define N_   16384
#define K_   8192
#define OUT_SZ   4194304
#define LOSS_OFF 4194304
#define IDX_OFF  4194305
#define MARGIN   0.3f    /* 8.1-sigma of 1-product pairwise score error (sigma~0.037) */

typedef __attribute__((ext_vector_type(8)))  short short8;
typedef __attribute__((ext_vector_type(4)))  float f32x4;

// ---- ws layout (bytes): Bh 4MB | cnorm | list | cnt | fidx  (~4.36 MB, under proven >=10.26 MB) ----
#define BH_OFF    0u
#define CNORM_OFF 4194304u
#define LIST_OFF  4227072u
#define CNT_OFF   4292608u
#define FIDX_OFF  4292672u
#define WS_NEED   4358656u

// ---- fallback ws layout (round-1 proven) ----
#define FB_CNORM   0u
#define FB_BESTS   32768u
#define FB_BESTK   557056u
#define FB_FIDX    1081344u

__device__ __forceinline__ unsigned short f2bf_rne(float x) {
  unsigned u = __float_as_uint(x);
  unsigned r = (u + 0x7fffu + ((u >> 16) & 1u)) >> 16;
  return (unsigned short)r;
}
__device__ __forceinline__ float bf2f(unsigned short h) {
  return __uint_as_float(((unsigned)h) << 16);
}
__device__ __forceinline__ void gld16(const void* g, void* l) {
  __builtin_amdgcn_global_load_lds((const __attribute__((address_space(1))) unsigned*)g,
                                   (__attribute__((address_space(3))) unsigned*)l, 16, 0, 0);
}
__device__ __forceinline__ bool better(float sa, int ka, float sb, int kb) {
  return (sa > sb) || (sa == sb && ka < kb);
}
// merge sorted triple (b1..b3) into sorted triple (s1..s3); ties -> lower k
__device__ __forceinline__ void tri_merge(float& s1, int& k1, float& s2, int& k2,
                                          float& s3, int& k3,
                                          float b1, int c1, float b2, int c2,
                                          float b3, int c3) {
  if (!better(b1, c1, s1, k1)) {
    if (!better(b1, c1, s2, k2)) {              // s1, s2, best(s3, b1)
      if (better(b1, c1, s3, k3)) { s3 = b1; k3 = c1; }
    } else {                                    // s1, b1, best(s2, b2)
      bool w = better(s2, k2, b2, c2);
      s3 = w ? s2 : b2; k3 = w ? k2 : c2;
      s2 = b1; k2 = c1;
    }
  } else {
    if (better(s1, k1, b2, c2)) {               // b1, s1, best(s2, b2)
      bool w = better(s2, k2, b2, c2);
      s3 = w ? s2 : b2; k3 = w ? k2 : c2;
      s2 = s1; k2 = k1;
      s1 = b1; k1 = c1;
    } else {                                    // b1, b2, best(s1, b3)
      bool w = better(s1, k1, b3, c3);
      s3 = w ? s1 : b3; k3 = w ? k1 : c3;
      s1 = b1; k1 = c1;
      s2 = b2; k2 = c2;
    }
  }
}

// emb -> bf16-hi image + 0.5||e||^2, fused; zero loss + counter
__global__ __launch_bounds__(256) void conv_embn(const float* __restrict__ emb,
                                                 unsigned short* __restrict__ Bh,
                                                 float* __restrict__ cnorm,
                                                 float* __restrict__ loss_slot,
                                                 int* __restrict__ counter) {
  int tid = threadIdx.x, wave = tid >> 6, lane = tid & 63;
  int k = blockIdx.x * 4 + wave;
  float4 v = *(const float4*)(emb + (size_t)k * C_ + lane * 4);
  float ss = v.x*v.x + v.y*v.y + v.z*v.z + v.w*v.w;
  #pragma unroll
  for (int m = 32; m > 0; m >>= 1) ss += __shfl_xor(ss, m);
  if (lane == 0) cnorm[k] = 0.5f * ss;
  uint2 p;
  p.x = (unsigned)f2bf_rne(v.x) | ((unsigned)f2bf_rne(v.y) << 16);
  p.y = (unsigned)f2bf_rne(v.z) | ((unsigned)f2bf_rne(v.w) << 16);
  *(uint2*)&Bh[(size_t)k * C_ + lane * 4] = p;
  if (blockIdx.x == 0 && tid == 0) { *loss_slot = 0.0f; *counter = 0; }
}

// inputs [B,C,HW] fp32 -> bf16-hi A[n][c] (n=b*1024+hw), in d_out[0,8MB)
__global__ __launch_bounds__(256) void conv_inph(const float* __restrict__ inp,
                                                 unsigned short* __restrict__ Ah) {
  __shared__ float T[64][65];
  int tid = threadIdx.x;
  int nt = blockIdx.x >> 2, ct = blockIdx.x & 3;
  int n0 = nt * 64, c0 = ct * 64;
  int b = n0 >> 10, hw0 = n0 & 1023;
  const float* base = inp + (size_t)b * (C_ * HW_) + hw0;
  #pragma unroll
  for (int i = 0; i < 16; ++i) {
    int cl = i * 4 + (tid >> 6), nl = tid & 63;
    T[nl][cl] = base[(size_t)(c0 + cl) * HW_ + nl];
  }
  __syncthreads();
  #pragma unroll
  for (int i = 0; i < 16; ++i) {
    int nl = i * 4 + (tid >> 6), cl = tid & 63;
    Ah[(size_t)(n0 + nl) * C_ + c0 + cl] = f2bf_rne(T[nl][cl]);
  }
}

// 1-product hh MFMA GEMM; per-(row, 256-sub) top-3 records -> d_out[8MB,16MB).
// Block 128 rows x 1024 codes (4 subs); 4 waves 2x2; gld16 staging; XOR-swizzled LDS.
__global__ __launch_bounds__(256, 2) void k_gemm1p(const unsigned short* __restrict__ Ah,
                                                   const unsigned short* __restrict__ Bh,
                                                   const float* __restrict__ cnorm,
                                                   uint4* __restrict__ Rec) {
  // shorts: A [0,4096) | B [4096,12288)  (24 KB); chunk g at byte g*16 (A), 8192+g*16 (B)
  __shared__ __align__(16) unsigned short LDS[12288];
  __shared__ float    mS[2][128][3];
  __shared__ unsigned mP[2][128];

  const int tid = threadIdx.x, lane = tid & 63, wave = tid >> 6;
  const int wr = wave >> 1, wc = wave & 1;
  const int rb = blockIdx.x >> 3, kb = blockIdx.x & 7;
  const int row0 = rb * 128;
  const int qm = lane & 15, quad = lane >> 4;
  const int sw = (quad ^ (qm & 3)) * 8;

  for (int sub = 0; sub < 4; ++sub) {
    const int nbe = kb * 4 + sub;
    f32x4 acc[4][8];
    #pragma unroll
    for (int r = 0; r < 4; ++r)
      #pragma unroll
      for (int c = 0; c < 8; ++c)
        #pragma unroll
        for (int e = 0; e < 4; ++e) acc[r][c][e] = 0.0f;

    for (int ci = 0; ci < 8; ++ci) {
      const int c0 = ci * 32;
      __syncthreads();
      #pragma unroll
      for (int t = 0; t < 2; ++t) {                    // A: 512 chunks
        int g = t * 256 + tid;
        int row = g >> 2, chs = g & 3, ch = chs ^ (row & 3);
        gld16(Ah + (size_t)(row0 + row) * C_ + c0 + ch * 8, (char*)LDS + g * 16);
      }
      #pragma unroll
      for (int t = 0; t < 4; ++t) {                    // B: 1024 chunks
        int g = t * 256 + tid;
        int r = g >> 2, chs = g & 3, ch = chs ^ (r & 3);
        gld16(Bh + (size_t)(nbe * 256 + r) * C_ + c0 + ch * 8, (char*)LDS + 8192 + g * 16);
      }
      __syncthreads();

      short8 ah[4];
      #pragma unroll
      for (int rt = 0; rt < 4; ++rt) {
        int row = (wr * 4 + rt) * 16 + qm;             // A[m=lane&15][k=quad*8+j]
        ah[rt] = *(const short8*)&LDS[row * 32 + sw];
      }
      #pragma unroll
      for (int ch2 = 0; ch2 < 2; ++ch2) {
        short8 bh[4];
        #pragma unroll
        for (int q = 0; q < 4; ++q) {
          int ct = ch2 * 4 + q;
          int r = (wc * 8 + ct) * 16 + qm;             // B[n=lane&15][k=quad*8+j]
          bh[q] = *(const short8*)&LDS[4096 + r * 32 + sw];
        }
        #pragma unroll
        for (int rt = 0; rt < 4; ++rt)
          #pragma unroll
          for (int q = 0; q < 4; ++q)
            acc[rt][ch2 * 4 + q] =
              __builtin_amdgcn_mfma_f32_16x16x32_bf16(ah[rt], bh[q], acc[rt][ch2 * 4 + q], 0, 0, 0);
      }
    }

    // epilogue: per-row top-3 over this wave's 128-code half, cross-lane, then wc-merge
    const int colbase = nbe * 256 + wc * 128 + qm;     // C/D: col=lane&15, row=quad*4+reg
    float cn[8];
    #pragma unroll
    for (int ct = 0; ct < 8; ++ct) cn[ct] = cnorm[colbase + ct * 16];

    #pragma unroll
    for (int rt = 0; rt < 4; ++rt)
      #pragma unroll
      for (int rg = 0; rg < 4; ++rg) {
        float t1 = -3.4e38f, t2 = t1, t3 = t1; int j1 = 0, j2 = 0, j3 = 0;
        #pragma unroll
        for (int ct = 0; ct < 8; ++ct) {               // ct ascending = k ascending
          float s = acc[rt][ct][rg] - cn[ct];
          int kl = wc * 128 + qm + ct * 16;            // local k in [0,256)
          if (s > t1)      { t3=t2; j3=j2; t2=t1; j2=j1; t1=s; j1=kl; }
          else if (s > t2) { t3=t2; j3=j2; t2=s; j2=kl; }
          else if (s > t3) { t3=s; j3=kl; }
        }
        #pragma unroll
        for (int m = 1; m < 16; m <<= 1) {
          float b1 = __shfl_xor(t1, m), b2 = __shfl_xor(t2, m), b3 = __shfl_xor(t3, m);
          int   c1 = __shfl_xor(j1, m), c2 = __shfl_xor(j2, m), c3 = __shfl_xor(j3, m);
          tri_merge(t1, j1, t2, j2, t3, j3, b1, c1, b2, c2, b3, c3);
        }
        if (qm == 0) {
          int rowl = wr * 64 + rt * 16 + quad * 4 + rg;
          mS[wc][rowl][0] = t1; mS[wc][rowl][1] = t2; mS[wc][rowl][2] = t3;
          mP[wc][rowl] = (unsigned)j1 | ((unsigned)j2 << 8) | ((unsigned)j3 << 16);
        }
      }
    __syncthreads();
    if (tid < 128) {
      float s1 = mS[0][tid][0], s2 = mS[0][tid][1], s3 = mS[0][tid][2];
      unsigned pa = mP[0][tid];
      int k1 = pa & 255, k2 = (pa >> 8) & 255, k3 = (pa >> 16) & 255;
      float b1 = mS[1][tid][0], b2 = mS[1][tid][1], b3 = mS[1][tid][2];
      unsigned pb = mP[1][tid];
      tri_merge(s1, k1, s2, k2, s3, k3,
                b1, (int)(pb & 255), b2, (int)((pb >> 8) & 255), b3, (int)((pb >> 16) & 255));
      uint4 rec;
      rec.x = __float_as_uint(s1);
      rec.y = ((unsigned)f2bf_rne(s2) << 16) | (unsigned)f2bf_rne(s3);
      rec.z = (unsigned)k1 | ((unsigned)k2 << 8) | ((unsigned)k3 << 16);
      rec.w = 0u;
      Rec[(size_t)(row0 + tid) * 32 + nbe] = rec;
    }
    __syncthreads();
  }
}

// per row: global hh-max over 32 subs; count candidates within MARGIN; decide or flag
__global__ __launch_bounds__(256) void k_merge3(const uint4* __restrict__ Rec,
                                                int* __restrict__ fidx,
                                                float* __restrict__ outIdx,
                                                int* __restrict__ list,
                                                int* __restrict__ counter) {
  int row = blockIdx.x * 256 + threadIdx.x;
  const uint4* r = Rec + (size_t)row * 32;
  float g1 = -3.4e38f; int gk = 0;
  #pragma unroll
  for (int s = 0; s < 32; ++s) {
    float s1 = __uint_as_float(r[s].x);
    if (s1 > g1) { g1 = s1; gk = s * 256 + (int)(r[s].z & 255u); }
  }
  float thr = g1 - MARGIN;
  int cnt = 0;
  #pragma unroll
  for (int s = 0; s < 32; ++s) {
    uint4 v = r[s];
    cnt += (__uint_as_float(v.x) >= thr);
    cnt += (bf2f((unsigned short)(v.y >> 16)) >= thr);
    cnt += (bf2f((unsigned short)(v.y & 0xffffu)) >= thr);
  }
  if (cnt == 1) { fidx[row] = gk; outIdx[row] = (float)gk; }
  else { int p = atomicAdd(counter, 1); list[p] = row; }
}

// exact fp32 refine for flagged rows: candidates (<=96) from records, wave-per-candidate dots
__global__ __launch_bounds__(256) void k_refine(const float* __restrict__ inp,
                                                const float* __restrict__ emb,
                                                const float* __restrict__ cnorm,
                                                const uint4* __restrict__ Rec,
                                                const int* __restrict__ list,
                                                const int* __restrict__ counter,
                                                int* __restrict__ fidx,
                                                float* __restrict__ outIdx) {
  __shared__ float f[256];
  __shared__ float ls1[32];
  __shared__ int   ck[96];
  __shared__ float csc[96];
  __shared__ int   ncand;
  int tid = threadIdx.x, lane = tid & 63, wv = tid >> 6;
  int count = *counter;
  for (int i = blockIdx.x; i < count; i += 4096) {
    int row = list[i];
    __syncthreads();
    f[tid] = inp[(size_t)(row >> 10) * (C_ * HW_) + (size_t)tid * HW_ + (row & 1023)];
    if (tid == 0) ncand = 0;
    if (tid < 32) ls1[tid] = __uint_as_float(Rec[(size_t)row * 32 + tid].x);
    __syncthreads();
    float g1 = ls1[0];
    #pragma unroll
    for (int s = 1; s < 32; ++s) g1 = fmaxf(g1, ls1[s]);
    float thr = g1 - MARGIN;
    if (tid < 32) {
      uint4 v = Rec[(size_t)row * 32 + tid];
      float s1 = __uint_as_float(v.x);
      float s2 = bf2f((unsigned short)(v.y >> 16));
      float s3 = bf2f((unsigned short)(v.y & 0xffffu));
      int b = tid * 256;
      if (s1 >= thr) { int p = atomicAdd(&ncand, 1); ck[p] = b + (int)(v.z & 255u); }
      if (s2 >= thr) { int p = atomicAdd(&ncand, 1); ck[p] = b + (int)((v.z >> 8) & 255u); }
      if (s3 >= thr) { int p = atomicAdd(&ncand, 1); ck[p] = b + (int)((v.z >> 16) & 255u); }
    }
    __syncthreads();
    int nc = ncand;
    for (int c = wv; c < nc; c += 4) {
      int k = ck[c];
      float4 e = ((const float4*)(emb + (size_t)k * C_))[lane];
      float d = f[lane*4]*e.x + f[lane*4+1]*e.y + f[lane*4+2]*e.z + f[lane*4+3]*e.w;
      #pragma unroll
      for (int m = 32; m > 0; m >>= 1) d += __shfl_xor(d, m);
      if (lane == 0) csc[c] = d - cnorm[k];
    }
    __syncthreads();
    if (tid == 0) {
      float bs = csc[0]; int bk = ck[0];
      for (int c = 1; c < nc; ++c)
        if (csc[c] > bs || (csc[c] == bs && ck[c] < bk)) { bs = csc[c]; bk = ck[c]; }
      fidx[row] = bk; outIdx[row] = (float)bk;
    }
    __syncthreads();
  }
}

// gather emb[idx] -> NCHW output (overwrites the scratch in d_out) + commitment loss
__global__ __launch_bounds__(256) void k_out(const float* __restrict__ inp,
                                             const float* __restrict__ emb,
                                             const int* __restrict__ fidx,
                                             float* __restrict__ out,
                                             float* __restrict__ loss) {
  __shared__ float Q[32][260];
  int tid = threadIdx.x;
  int n0 = blockIdx.x * 32, b = n0 >> 10, hw0 = n0 & 1023;
  #pragma unroll
  for (int p = 0; p < 8; ++p) {
    int r = p * 4 + (tid >> 6);
    int kq = fidx[n0 + r];
    float4 v = *(const float4*)(emb + (size_t)kq * C_ + (tid & 63) * 4);
    *(float4*)&Q[r][(tid & 63) * 4] = v;
  }
  __syncthreads();
  int hwl = tid & 31, cl = tid >> 5;
  float lsum = 0.0f;
  #pragma unroll
  for (int p = 0; p < 32; ++p) {
    int c = p * 8 + cl;
    size_t a = (size_t)b * (C_ * HW_) + (size_t)c * HW_ + hw0 + hwl;
    float q = Q[hwl][c];
    float x = inp[a];
    out[a] = q;
    float dd = q - x; lsum += dd * dd;
  }
  #pragma unroll
  for (int m = 32; m > 0; m >>= 1) lsum += __shfl_xor(lsum, m);
  __shared__ float red[4];
  if ((tid & 63) == 0) red[tid >> 6] = lsum;
  __syncthreads();
  if (tid == 0)
    atomicAdd(loss, (red[0] + red[1] + red[2] + red[3]) * (0.25f / (float)OUT_SZ));
}

// ---------------- fallback path (round-1 fp32, proven) ----------------
__global__ __launch_bounds__(256) void k_norms_fb(const float* __restrict__ emb,
                                                  float* __restrict__ cnorm,
                                                  float* __restrict__ loss_slot) {
  int tid = threadIdx.x, wave = tid >> 6, lane = tid & 63;
  int k = blockIdx.x * 4 + wave;
  float4 v = *(const float4*)(emb + k * C_ + lane * 4);
  float s = v.x*v.x + v.y*v.y + v.z*v.z + v.w*v.w;
  #pragma unroll
  for (int m = 32; m > 0; m >>= 1) s += __shfl_xor(s, m);
  if (lane == 0) cnorm[k] = 0.5f * s;
  if (blockIdx.x == 0 && tid == 0) *loss_slot = 0.0f;
}

__global__ __launch_bounds__(256) void k_score_fb(const float* __restrict__ inp,
                                                  const float* __restrict__ emb,
                                                  const float* __restrict__ cnorm,
                                                  float* __restrict__ bestS,
                                                  int*   __restrict__ bestK) {
  __shared__ float As[16][132];
  __shared__ float Bs[16][132];
  const int tid = threadIdx.x;
  const int tx = tid & 15, ty = tid >> 4;
  const int rt = blockIdx.x >> 3, ks = blockIdx.x & 7;
  const int row0 = rt * 128;
  const float* Abase = inp + (row0 >> 10) * (C_ * HW_) + (row0 & 1023);
  const int kbase = ks * 1024;
  const int m4  = (tid & 31) << 2;
  const int ccA = tid >> 5;
  const int cc4 = (tid & 3) << 2;
  const int kkB = tid >> 2;

  float rS[8]; int rK[8];
  #pragma unroll
  for (int r = 0; r < 8; ++r) { rS[r] = -3.4e38f; rK[r] = 0; }

  for (int kt = 0; kt < 8; ++kt) {
    const int k0 = kbase + kt * 128;
    float acc[8][8];
    #pragma unroll
    for (int r = 0; r < 8; ++r)
      #pragma unroll
      for (int c = 0; c < 8; ++c) acc[r][c] = 0.f;

    for (int ci = 0; ci < 16; ++ci) {
      const int c0 = ci * 16;
      __syncthreads();
      #pragma unroll
      for (int p = 0; p < 2; ++p) {
        int cc = ccA + p * 8;
        float4 v = *(const float4*)(Abase + (c0 + cc) * HW_ + m4);
        *(float4*)(&As[cc][m4]) = v;
      }
      #pragma unroll
      for (int p = 0; p < 2; ++p) {
        int k = kkB + p * 64;
        float4 v = *(const float4*)(emb + (size_t)(k0 + k) * C_ + c0 + cc4);
        Bs[cc4 + 0][k] = v.x; Bs[cc4 + 1][k] = v.y;
        Bs[cc4 + 2][k] = v.z; Bs[cc4 + 3][k] = v.w;
      }
      __syncthreads();
      #pragma unroll
      for (int cc = 0; cc < 16; ++cc) {
        float4 a0 = *(const float4*)(&As[cc][ty * 8]);
        float4 a1 = *(const float4*)(&As[cc][ty * 8 + 4]);
        float4 b0 = *(const float4*)(&Bs[cc][tx * 8]);
        float4 b1 = *(const float4*)(&Bs[cc][tx * 8 + 4]);
        float a[8] = {a0.x, a0.y, a0.z, a0.w, a1.x, a1.y, a1.z, a1.w};
        float b[8] = {b0.x, b0.y, b0.z, b0.w, b1.x, b1.y, b1.z, b1.w};
        #pragma unroll
        for (int r = 0; r < 8; ++r)
          #pragma unroll
          for (int c = 0; c < 8; ++c) acc[r][c] += a[r] * b[c];
      }
    }
    float cn[8];
    {
      float4 c0v = *(const float4*)(cnorm + k0 + tx * 8);
      float4 c1v = *(const float4*)(cnorm + k0 + tx * 8 + 4);
      cn[0] = c0v.x; cn[1] = c0v.y; cn[2] = c0v.z; cn[3] = c0v.w;
      cn[4] = c1v.x; cn[5] = c1v.y; cn[6] = c1v.z; cn[7] = c1v.w;
    }
    #pragma unroll
    for (int r = 0; r < 8; ++r)
      #pragma unroll
      for (int c = 0; c < 8; ++c) {
        float s = acc[r][c] - cn[c];
        if (s > rS[r]) { rS[r] = s; rK[r] = k0 + tx * 8 + c; }
      }
  }
  #pragma unroll
  for (int r = 0; r < 8; ++r) {
    float s = rS[r]; int kk = rK[r];
    #pragma unroll
    for (int m = 1; m < 16; m <<= 1) {
      float so = __shfl_xor(s, m);
      int   ko = __shfl_xor(kk, m);
      if (so > s || (so == s && ko < kk)) { s = so; kk = ko; }
    }
    if (tx == 0) {
      int row = row0 + ty * 8 + r;
      bestS[ks * N_ + row] = s;
      bestK[ks * N_ + row] = kk;
    }
  }
}

__global__ __launch_bounds__(256) void k_merge_fb(const float* __restrict__ bestS,
                                                  const int*   __restrict__ bestK,
                                                  float* __restrict__ out_idx,
                                                  int*   __restrict__ fidx) {
  int n = blockIdx.x * 256 + threadIdx.x;
  float bs = -3.4e38f; int bk = 0x7fffffff;
  #pragma unroll
  for (int s = 0; s < 8; ++s) {
    float v = bestS[s * N_ + n];
    int  kk = bestK[s * N_ + n];
    if (v > bs || (v == bs && kk < bk)) { bs = v; bk = kk; }
  }
  out_idx[n] = (float)bk;
  fidx[n] = bk;
}

extern "C" void kernel_launch(void* const* d_in, const int* in_sizes, int n_in,
                              void* d_out, int out_size, void* d_ws, size_t ws_size,
                              hipStream_t stream) {
  const float* inp = (const float*)d_in[0];
  const float* emb = (const float*)d_in[1];
  float* out = (float*)d_out;
  char* ws = (char*)d_ws;

  if (ws_size >= (size_t)WS_NEED) {
    unsigned short* Ah = (unsigned short*)d_out;             // [0, 8MB) of d_out
    uint4* Rec = (uint4*)((char*)d_out + 8388608u);          // [8MB, 16MB) of d_out
    unsigned short* Bh = (unsigned short*)(ws + BH_OFF);
    float* cnorm   = (float*)(ws + CNORM_OFF);
    int*   list    = (int*)(ws + LIST_OFF);
    int*   counter = (int*)(ws + CNT_OFF);
    int*   fidx    = (int*)(ws + FIDX_OFF);

    conv_embn <<<K_ / 4, 256, 0, stream>>>(emb, Bh, cnorm, out + LOSS_OFF, counter);
    conv_inph <<<1024,   256, 0, stream>>>(inp, Ah);
    k_gemm1p  <<<1024,   256, 0, stream>>>(Ah, Bh, cnorm, Rec);
    k_merge3  <<<N_/256, 256, 0, stream>>>(Rec, fidx, out + IDX_OFF, list, counter);
    k_refine  <<<4096,   256, 0, stream>>>(inp, emb, cnorm, Rec, list, counter,
                                           fidx, out + IDX_OFF);
    k_out     <<<N_/32,  256, 0, stream>>>(inp, emb, fidx, out, out + LOSS_OFF);
  } else {
    float* cnorm = (float*)(ws + FB_CNORM);
    float* bestS = (float*)(ws + FB_BESTS);
    int*   bestK = (int*)(ws + FB_BESTK);
    int*   fidx  = (int*)(ws + FB_FIDX);

    k_norms_fb <<<K_ / 4, 256, 0, stream>>>(emb, cnorm, out + LOSS_OFF);
    k_score_fb <<<1024,   256, 0, stream>>>(inp, emb, cnorm, bestS, bestK);
    k_merge_fb <<<N_/256, 256, 0, stream>>>(bestS, bestK, out + IDX_OFF, fidx);
    k_out      <<<OUT_SZ/8192, 256, 0, stream>>>(inp, emb, fidx, out, out + LOSS_OFF);
  }
}